// Round 4
// baseline (767.489 us; speedup 1.0000x reference)
//
#include <hip/hip_runtime.h>

#define DIVN 8
#define NB 32
#define NBLK 6144                 // 96 images * 64 blocks
#define ROWS_PER_CHUNK 64
#define NCHUNK 1536               // img*16 + bi*2 + half

typedef float floatx4 __attribute__((ext_vector_type(4)));

// Fused: per-chunk stats + last-WG-done final pair reduction.
__global__ __launch_bounds__(256) void fused_kernel(
    const float* __restrict__ x,
    double* __restrict__ wsum,    // [2][NBLK]
    float* __restrict__ wmn,      // [2][NBLK]
    float* __restrict__ wmx,      // [2][NBLK]
    unsigned int* __restrict__ counter,
    float* __restrict__ out) {
    const int ch  = blockIdx.x;           // 0..1535
    const int tid = threadIdx.x;          // 0..255
    const float* base = x + (size_t)ch * (ROWS_PER_CHUNK * 1024) + tid * 4;

    double s = 0.0;
    float mn = 3.402823466e38f;
    float mx = -3.402823466e38f;

    #pragma unroll 8
    for (int i = 0; i < ROWS_PER_CHUNK; ++i) {
        const floatx4 v = __builtin_nontemporal_load(
            reinterpret_cast<const floatx4*>(base + (size_t)i * 1024));
        s += (double)((v.x + v.y) + (v.z + v.w));
        mn = fminf(mn, fminf(fminf(v.x, v.y), fminf(v.z, v.w)));
        mx = fmaxf(mx, fmaxf(fmaxf(v.x, v.y), fmaxf(v.z, v.w)));
    }

    // Reduce within 32-lane groups (one group per bj).
    for (int off = 16; off > 0; off >>= 1) {
        s  += __shfl_down(s, off, 32);
        mn  = fminf(mn, __shfl_down(mn, off, 32));
        mx  = fmaxf(mx, __shfl_down(mx, off, 32));
    }

    if ((tid & 31) == 0) {
        const int bj   = tid >> 5;
        const int half = ch & 1;
        const int bi   = (ch >> 1) & 7;
        const int img  = ch >> 4;
        const int g    = half * NBLK + img * 64 + bi * 8 + bj;
        // Agent-scope release stores: performed at coherence point (cross-XCD safe).
        __hip_atomic_store(&wsum[g], s,  __ATOMIC_RELEASE, __HIP_MEMORY_SCOPE_AGENT);
        __hip_atomic_store(&wmn[g],  mn, __ATOMIC_RELEASE, __HIP_MEMORY_SCOPE_AGENT);
        __hip_atomic_store(&wmx[g],  mx, __ATOMIC_RELEASE, __HIP_MEMORY_SCOPE_AGENT);
    }
    __syncthreads();

    __shared__ int lastflag;
    if (tid == 0) {
        const unsigned prev = __hip_atomic_fetch_add(
            counter, 1u, __ATOMIC_ACQ_REL, __HIP_MEMORY_SCOPE_AGENT);
        lastflag = (prev == NCHUNK - 1);
    }
    __syncthreads();
    if (!lastflag) return;

    // ---- Final pair reduction (exactly one WG reaches here) ----
    double acc = 0.0;
    for (int item = tid; item < NB * 64; item += 256) {
        const int p = item & 63;        // bi*8 + bj
        const int b = item >> 6;
        float m[3], n[3], X[3];
        #pragma unroll
        for (int c = 0; c < 3; ++c) {
            const int i = (b * 3 + c) * 64 + p;
            const double s0 = __hip_atomic_load(&wsum[i],        __ATOMIC_RELAXED, __HIP_MEMORY_SCOPE_AGENT);
            const double s1 = __hip_atomic_load(&wsum[NBLK + i], __ATOMIC_RELAXED, __HIP_MEMORY_SCOPE_AGENT);
            const float  n0 = __hip_atomic_load(&wmn[i],         __ATOMIC_RELAXED, __HIP_MEMORY_SCOPE_AGENT);
            const float  n1 = __hip_atomic_load(&wmn[NBLK + i],  __ATOMIC_RELAXED, __HIP_MEMORY_SCOPE_AGENT);
            const float  x0 = __hip_atomic_load(&wmx[i],         __ATOMIC_RELAXED, __HIP_MEMORY_SCOPE_AGENT);
            const float  x1 = __hip_atomic_load(&wmx[NBLK + i],  __ATOMIC_RELAXED, __HIP_MEMORY_SCOPE_AGENT);
            m[c] = (float)((s0 + s1) * (1.0 / 16384.0));
            n[c] = fminf(n0, n1);
            X[c] = fmaxf(x0, x1);
        }
        if (!((n[0] > X[1]) || (X[0] < n[1]))) { const float d = m[0] - m[1]; acc += (double)(d * d); }
        if (!((n[1] > X[2]) || (X[1] < n[2]))) { const float d = m[1] - m[2]; acc += (double)(d * d); }
        if (!((n[0] > X[2]) || (X[0] < n[2]))) { const float d = m[0] - m[2]; acc += (double)(d * d); }
    }

    __shared__ double sacc[256];
    sacc[tid] = acc;
    __syncthreads();
    for (int off = 128; off > 0; off >>= 1) {
        if (tid < off) sacc[tid] += sacc[tid + off];
        __syncthreads();
    }
    if (tid == 0) out[0] = (float)(sacc[0] * (1.0 / (DIVN * DIVN)));
}

extern "C" void kernel_launch(void* const* d_in, const int* in_sizes, int n_in,
                              void* d_out, int out_size, void* d_ws, size_t ws_size,
                              hipStream_t stream) {
    const float* x = (const float*)d_in[0];
    float* out = (float*)d_out;

    // ws layout: doubles first (alignment), then floats, then the counter.
    double*       wsum    = (double*)d_ws;                 // 2*NBLK doubles
    float*        wmn     = (float*)(wsum + 2 * NBLK);     // 2*NBLK floats
    float*        wmx     = wmn + 2 * NBLK;                // 2*NBLK floats
    unsigned int* counter = (unsigned int*)(wmx + 2 * NBLK);

    hipMemsetAsync(counter, 0, sizeof(unsigned int), stream);
    fused_kernel<<<NCHUNK, 256, 0, stream>>>(x, wsum, wmn, wmx, counter, out);
}

// Round 5
// 79.536 us; speedup vs baseline: 9.6495x; 9.6495x over previous
//
#include <hip/hip_runtime.h>

#define DIVN 8
#define NB 32
#define NBLK 6144                 // 96 images * 64 blocks
#define ROWS_PER_CHUNK 64
#define NCHUNK 1536               // img*16 + bi*2 + half

typedef float floatx4 __attribute__((ext_vector_type(4)));

// Fused stats + last-WG-done finale. ALL cross-WG communication is via
// relaxed device-scope atomic RMWs (coherence-point ops, no L2 wb/inv).
__global__ __launch_bounds__(256) void fused_kernel(
    const float* __restrict__ x,
    double* __restrict__ sumd,        // [NBLK] zero-init
    unsigned int* __restrict__ mni,   // [NBLK] 0xFFFFFFFF-init, uint-min of float bits
    unsigned int* __restrict__ mxi,   // [NBLK] zero-init,       uint-max of float bits
    unsigned int* __restrict__ counter,
    float* __restrict__ out) {
    const int ch  = blockIdx.x;           // 0..1535
    const int tid = threadIdx.x;          // 0..255
    const float* base = x + (size_t)ch * (ROWS_PER_CHUNK * 1024) + tid * 4;

    double s = 0.0;
    float mn = 3.402823466e38f;
    float mx = -3.402823466e38f;

    #pragma unroll 8
    for (int i = 0; i < ROWS_PER_CHUNK; ++i) {
        const floatx4 v = __builtin_nontemporal_load(
            reinterpret_cast<const floatx4*>(base + (size_t)i * 1024));
        s += (double)((v.x + v.y) + (v.z + v.w));
        mn = fminf(mn, fminf(fminf(v.x, v.y), fminf(v.z, v.w)));
        mx = fmaxf(mx, fmaxf(fmaxf(v.x, v.y), fmaxf(v.z, v.w)));
    }

    // Reduce within 32-lane groups (one group per bj).
    for (int off = 16; off > 0; off >>= 1) {
        s  += __shfl_down(s, off, 32);
        mn  = fminf(mn, __shfl_down(mn, off, 32));
        mx  = fmaxf(mx, __shfl_down(mx, off, 32));
    }

    if ((tid & 31) == 0) {
        const int bj  = tid >> 5;
        const int bi  = (ch >> 1) & 7;
        const int img = ch >> 4;
        const int g   = img * 64 + bi * 8 + bj;
        // Relaxed device-scope RMWs: cross-XCD coherent, no cache maintenance.
        atomicAdd(&sumd[g], s);
        atomicMin(&mni[g], __float_as_uint(mn));
        atomicMax(&mxi[g], __float_as_uint(mx));
    }
    // vmcnt(0) drain before the barrier => RMWs performed at coherence point.
    __syncthreads();

    __shared__ int lastflag;
    if (tid == 0) {
        const unsigned prev = __hip_atomic_fetch_add(
            counter, 1u, __ATOMIC_RELAXED, __HIP_MEMORY_SCOPE_AGENT);
        lastflag = (prev == NCHUNK - 1);
    }
    __syncthreads();
    if (!lastflag) return;

    // ---- Finale: exactly one WG, after all 1536 WGs' RMWs are performed ----
    double acc = 0.0;
    for (int item = tid; item < NB * 64; item += 256) {
        const int p = item & 63;        // bi*8 + bj
        const int b = item >> 6;
        float m[3], n[3], X[3];
        #pragma unroll
        for (int c = 0; c < 3; ++c) {
            const int i = (b * 3 + c) * 64 + p;
            const double sd   = __hip_atomic_load(&sumd[i], __ATOMIC_RELAXED, __HIP_MEMORY_SCOPE_AGENT);
            const unsigned ni = __hip_atomic_load(&mni[i],  __ATOMIC_RELAXED, __HIP_MEMORY_SCOPE_AGENT);
            const unsigned xi = __hip_atomic_load(&mxi[i],  __ATOMIC_RELAXED, __HIP_MEMORY_SCOPE_AGENT);
            m[c] = (float)(sd * (1.0 / 16384.0));
            n[c] = __uint_as_float(ni);
            X[c] = __uint_as_float(xi);
        }
        if (!((n[0] > X[1]) || (X[0] < n[1]))) { const float d = m[0] - m[1]; acc += (double)(d * d); }
        if (!((n[1] > X[2]) || (X[1] < n[2]))) { const float d = m[1] - m[2]; acc += (double)(d * d); }
        if (!((n[0] > X[2]) || (X[0] < n[2]))) { const float d = m[0] - m[2]; acc += (double)(d * d); }
    }

    __shared__ double sacc[256];
    sacc[tid] = acc;
    __syncthreads();
    for (int off = 128; off > 0; off >>= 1) {
        if (tid < off) sacc[tid] += sacc[tid + off];
        __syncthreads();
    }
    if (tid == 0) out[0] = (float)(sacc[0] * (1.0 / (DIVN * DIVN)));
}

extern "C" void kernel_launch(void* const* d_in, const int* in_sizes, int n_in,
                              void* d_out, int out_size, void* d_ws, size_t ws_size,
                              hipStream_t stream) {
    const float* x = (const float*)d_in[0];
    float* out = (float*)d_out;

    // ws layout (bytes):
    //   [0,       49152)  sumd   : 6144 doubles, zero-init
    //   [49152,   73728)  mxi    : 6144 uints,   zero-init
    //   [73728,   73732)  counter: 1 uint,       zero-init
    //   [73744,   98320)  mni    : 6144 uints,   0xFF-init
    char* ws = (char*)d_ws;
    double*       sumd    = (double*)(ws);
    unsigned int* mxi     = (unsigned int*)(ws + 49152);
    unsigned int* counter = (unsigned int*)(ws + 73728);
    unsigned int* mni     = (unsigned int*)(ws + 73744);

    hipMemsetAsync(ws, 0x00, 73732, stream);            // sumd + mxi + counter
    hipMemsetAsync(ws + 73744, 0xFF, 6144 * 4, stream); // mni
    fused_kernel<<<NCHUNK, 256, 0, stream>>>(x, sumd, mni, mxi, counter, out);
}